// Round 6
// baseline (229.492 us; speedup 1.0000x reference)
//
#include <hip/hip_runtime.h>

#define N 20000
#define E 200000
#define IN 128
#define OUT 128
#define NB 8
#define SI 16
#define SO 16
#define R 230
#define T 365

// Scratch in module .bss (zero-initialized at load). d_ws untouched;
// kernel_launch does plain kernel launches only (graph-capture safe).
// Counter-zeroing invariant: node_kernel's tail re-zeroes all counters for
// the NEXT launch; the first launch relies on .bss zero-init.
__device__ float  g_W_t[(size_t)R * NB * SO * SI]; // W transposed: [r][b][ol][i]
__device__ ushort g_msg[(size_t)E * OUT];          // messages (bf16), dst-sorted
__device__ int    g_cnt_d[N];
__device__ int    g_off_d[N];
__device__ int    g_cur_d[N];
__device__ int    g_cnt_r[R * 16];                 // line-padded
__device__ int    g_cur_r[R * 16];
__device__ int    g_pos[E];                        // e -> dst-sorted position
__device__ int    g_eid_r[E];                      // edge ids sorted by relation
__device__ int    g_total_d;
__device__ int    g_total_r;

__device__ __forceinline__ ushort f2bf(float f) {  // RNE float->bf16
    unsigned u = __float_as_uint(f);
    return (ushort)((u + 0x7fffu + ((u >> 16) & 1u)) >> 16);
}
__device__ __forceinline__ float bf2f(ushort v) {
    return __uint_as_float((unsigned)v << 16);
}

// Histograms (counters pre-zeroed by previous launch / .bss) + W transpose
// (independent work, hidden under the atomic traffic).
__global__ __launch_bounds__(256) void hist_kernel(
        const float* __restrict__ weight,
        const int* __restrict__ edge_dst,
        const int* __restrict__ edge_type) {
    __shared__ int lh[R];
    const int tid  = threadIdx.x;
    const int gtid = blockIdx.x * 256 + tid;
    // W transpose into [r][b][ol][i]
    for (int t = gtid; t < R * NB * SI * SO; t += gridDim.x * 256) {
        int r  = t >> 11;
        int b  = (t >> 8) & 7;
        int ol = (t >> 4) & 15;
        int i  = t & 15;
        g_W_t[t] = weight[(long)r * 2048 + b * 256 + i * 16 + ol];
    }
    for (int j = tid; j < R; j += 256) lh[j] = 0;
    __syncthreads();
    for (long e = gtid; e < E; e += (long)gridDim.x * 256) {
        atomicAdd(&g_cnt_d[edge_dst[e]], 1);
        atomicAdd(&lh[edge_type[e]], 1);
    }
    __syncthreads();
    for (int j = tid; j < R; j += 256)
        if (lh[j]) atomicAdd(&g_cnt_r[j * 16], lh[j]);
}

// Wave-aggregated bump allocation (one global atomic per wave).
__global__ __launch_bounds__(256) void alloc_kernel() {
    int idx  = blockIdx.x * blockDim.x + threadIdx.x;
    int lane = threadIdx.x & 63;
    const int NPAD = 20032;                       // 313 waves, wave-aligned
    if (idx < NPAD) {
        int c = (idx < N) ? g_cnt_d[idx] : 0;
        int x = c;
        for (int d = 1; d < 64; d <<= 1) {
            int y = __shfl_up(x, d);
            if (lane >= d) x += y;
        }
        int base = 0;
        if (lane == 63) base = atomicAdd(&g_total_d, x);
        base = __shfl(base, 63);
        if (idx < N) {
            int off = base + x - c;
            g_off_d[idx] = off;
            g_cur_d[idx] = off;
        }
    } else if (idx < NPAD + 256) {
        int j = idx - NPAD;
        int c = (j < R) ? g_cnt_r[j * 16] : 0;
        int x = c;
        for (int d = 1; d < 64; d <<= 1) {
            int y = __shfl_up(x, d);
            if (lane >= d) x += y;
        }
        int base = 0;
        if (lane == 63) base = atomicAdd(&g_total_r, x);
        base = __shfl(base, 63);
        if (j < R) g_cur_r[j * 16] = base + x - c;
    }
}

__global__ void scatter_kernel(const int* __restrict__ edge_dst,
                               const int* __restrict__ edge_type) {
    int e = blockIdx.x * blockDim.x + threadIdx.x;
    if (e < E) {
        g_pos[e] = atomicAdd(&g_cur_d[edge_dst[e]], 1);
        int pr = atomicAdd(&g_cur_r[edge_type[e] * 16], 1);
        g_eid_r[pr] = e;
    }
}

// Block-pipelined message kernel, 32-edge tiles (halved from round 4 to cut
// LDS 34.8->17.4 KB: occupancy 4 -> 8 blocks/CU). Cooperative meta load,
// cooperative h-row gather into LDS (independent float4 loads, no dependent
// chains), compute with W[r] in registers (single-relation fast path ~97%
// of 32-tiles). msg stored as bf16 (RNE) at dst-sorted position with
// nontemporal stores (read-once data; keeps h/W_t cache-resident).
// E = 6250 * 32 exactly — no tail.
__global__ __launch_bounds__(256) void msg_kernel(
        const float* __restrict__ h,
        const float* __restrict__ edge_norm,
        const int* __restrict__ edge_src,
        const int* __restrict__ edge_type) {
    __shared__ __attribute__((aligned(16))) float hsm[32 * 132];
    __shared__ int   ssrc[32], stype[32], spos[32];
    __shared__ float snorm[32];

    const int tid = threadIdx.x;
    const int lo  = blockIdx.x * 32;

    if (tid < 32) {
        int e = g_eid_r[lo + tid];
        ssrc[tid]  = edge_src[e];
        stype[tid] = edge_type[e];
        snorm[tid] = edge_norm[e];
        spos[tid]  = g_pos[e];
    }
    __syncthreads();

    // gather 32 h-rows: 8 threads/row, 4 float4 each (128B-coalesced per row)
    {
        const int row = tid >> 3;
        const int c0  = (tid & 7) * 4;
        const float* hp = h + (long)ssrc[row] * IN;
        float* dst = &hsm[row * 132];
#pragma unroll
        for (int j = 0; j < 4; ++j) {
            float4 v = *reinterpret_cast<const float4*>(hp + c0 + 32 * j);
            *reinterpret_cast<float4*>(dst + c0 + 32 * j) = v;
        }
    }
    __syncthreads();

    const int slot = tid >> 7;           // 0,1
    const int o    = tid & 127;
    const int b    = o >> 4;
    const int ol   = o & 15;

#define MSG_BODY(K, W0, W1, W2, W3)                                          \
    {                                                                        \
        const float* hrow = &hsm[(K) * 132 + b * 16];                        \
        float4 h0 = *reinterpret_cast<const float4*>(hrow);                  \
        float4 h1 = *reinterpret_cast<const float4*>(hrow + 4);              \
        float4 h2 = *reinterpret_cast<const float4*>(hrow + 8);              \
        float4 h3 = *reinterpret_cast<const float4*>(hrow + 12);             \
        float m0 = 0.f, m1 = 0.f;                                            \
        m0 = fmaf(h0.x, W0.x, m0); m0 = fmaf(h0.y, W0.y, m0);                \
        m0 = fmaf(h0.z, W0.z, m0); m0 = fmaf(h0.w, W0.w, m0);                \
        m1 = fmaf(h1.x, W1.x, m1); m1 = fmaf(h1.y, W1.y, m1);                \
        m1 = fmaf(h1.z, W1.z, m1); m1 = fmaf(h1.w, W1.w, m1);                \
        m0 = fmaf(h2.x, W2.x, m0); m0 = fmaf(h2.y, W2.y, m0);                \
        m0 = fmaf(h2.z, W2.z, m0); m0 = fmaf(h2.w, W2.w, m0);                \
        m1 = fmaf(h3.x, W3.x, m1); m1 = fmaf(h3.y, W3.y, m1);                \
        m1 = fmaf(h3.z, W3.z, m1); m1 = fmaf(h3.w, W3.w, m1);                \
        __builtin_nontemporal_store(f2bf(snorm[K] * (m0 + m1)),              \
                                    &g_msg[(long)spos[K] * OUT + o]);        \
    }

    if (stype[0] == stype[31]) {
        const float4* wp = reinterpret_cast<const float4*>(
            g_W_t + (long)stype[0] * 2048 + b * 256 + ol * 16);
        float4 w0 = wp[0], w1 = wp[1], w2 = wp[2], w3 = wp[3];
#pragma unroll 4
        for (int k = slot; k < 32; k += 2)
            MSG_BODY(k, w0, w1, w2, w3)
    } else {
        int rcur = -1;
        float4 w0, w1, w2, w3;
        for (int k = slot; k < 32; k += 2) {
            int r = stype[k];
            if (r != rcur) {
                const float4* wp = reinterpret_cast<const float4*>(
                    g_W_t + (long)r * 2048 + b * 256 + ol * 16);
                w0 = wp[0]; w1 = wp[1]; w2 = wp[2]; w3 = wp[3];
                rcur = r;
            }
            MSG_BODY(k, w0, w1, w2, w3)
        }
    }
#undef MSG_BODY
}

// Fused segment-sum (bf16 msg, nontemporal) + self-loop GEMM + epilogue +
// time-embedding gather. 8 nodes/block, 128 threads -> 2500 blocks.
// Tail re-zeroes all counters for the next launch (invariant).
__global__ __launch_bounds__(128) void node_kernel(
        const float* __restrict__ h,
        const float* __restrict__ node_norm,
        const float* __restrict__ h_bias,
        const float* __restrict__ loop_weight,
        const float* __restrict__ time_embed,
        const int* __restrict__ time_idx,
        float* __restrict__ out) {
    __shared__ float hsm[IN * 8];        // hsm[i*8 + nl]
    const int o    = threadIdx.x;
    const int base = blockIdx.x * 8;

    for (int k = o; k < 8 * IN; k += 128) {
        int nl = k >> 7;
        int i  = k & 127;
        hsm[i * 8 + nl] = h[(long)(base + nl) * IN + i];
    }
    __syncthreads();

    // contiguous segment sums (msg in dst order), 4-way partials
    float acc[8];
#pragma unroll
    for (int nl = 0; nl < 8; ++nl) {
        int n  = base + nl;
        int st = g_off_d[n];
        int cn = g_cnt_d[n];
        float a0 = 0.f, a1 = 0.f, a2 = 0.f, a3 = 0.f;
        const ushort* mp = g_msg + (long)st * OUT + o;
        int k = 0;
        for (; k + 3 < cn; k += 4) {
            a0 += bf2f(__builtin_nontemporal_load(&mp[(long)(k + 0) * OUT]));
            a1 += bf2f(__builtin_nontemporal_load(&mp[(long)(k + 1) * OUT]));
            a2 += bf2f(__builtin_nontemporal_load(&mp[(long)(k + 2) * OUT]));
            a3 += bf2f(__builtin_nontemporal_load(&mp[(long)(k + 3) * OUT]));
        }
        for (; k < cn; ++k)
            a0 += bf2f(__builtin_nontemporal_load(&mp[(long)k * OUT]));
        acc[nl] = ((a0 + a1) + (a2 + a3)) * node_norm[n];
    }

    // self-loop GEMM: 8-wide w-load pipeline, float4 LDS broadcasts
    float sl[8];
#pragma unroll
    for (int nl = 0; nl < 8; ++nl) sl[nl] = 0.f;

    for (int i0 = 0; i0 < IN; i0 += 8) {
        float w[8];
#pragma unroll
        for (int j = 0; j < 8; ++j)
            w[j] = loop_weight[(long)(i0 + j) * OUT + o];
#pragma unroll
        for (int j = 0; j < 8; ++j) {
            const float* row = &hsm[(i0 + j) * 8];
            float4 p0 = *reinterpret_cast<const float4*>(row);
            float4 p1 = *reinterpret_cast<const float4*>(row + 4);
            sl[0] = fmaf(p0.x, w[j], sl[0]); sl[1] = fmaf(p0.y, w[j], sl[1]);
            sl[2] = fmaf(p0.z, w[j], sl[2]); sl[3] = fmaf(p0.w, w[j], sl[3]);
            sl[4] = fmaf(p1.x, w[j], sl[4]); sl[5] = fmaf(p1.y, w[j], sl[5]);
            sl[6] = fmaf(p1.z, w[j], sl[6]); sl[7] = fmaf(p1.w, w[j], sl[7]);
        }
    }

    const float bias = h_bias[o];
#pragma unroll
    for (int nl = 0; nl < 8; ++nl) {
        int n = base + nl;
        float v = acc[nl] + bias + sl[nl];
        out[(long)n * OUT + o] = fmaxf(v, 0.f);
        out[(long)N * OUT + (long)n * IN + o] =
            time_embed[(long)time_idx[n] * IN + o];
    }

    // ---- next-launch counter zeroing (after all reads of g_cnt_d) ----
    __syncthreads();
    if (o < 8) g_cnt_d[base + o] = 0;
    {
        int j = blockIdx.x * 128 + o;           // blocks 0..28 cover R*16
        if (j < R * 16) g_cnt_r[j] = 0;
    }
    if (blockIdx.x == 0 && o == 0) { g_total_d = 0; g_total_r = 0; }
}

extern "C" void kernel_launch(void* const* d_in, const int* in_sizes, int n_in,
                              void* d_out, int out_size, void* d_ws, size_t ws_size,
                              hipStream_t stream) {
    const float* h           = (const float*)d_in[0];
    const float* edge_norm   = (const float*)d_in[1];
    const float* node_norm   = (const float*)d_in[2];
    const float* weight      = (const float*)d_in[3];
    const float* h_bias      = (const float*)d_in[4];
    const float* loop_weight = (const float*)d_in[5];
    const float* time_embed  = (const float*)d_in[6];
    const int*   edge_src    = (const int*)d_in[7];
    const int*   edge_dst    = (const int*)d_in[8];
    const int*   edge_type   = (const int*)d_in[9];
    const int*   time_idx    = (const int*)d_in[10];
    float* out = (float*)d_out;

    hist_kernel<<<400, 256, 0, stream>>>(weight, edge_dst, edge_type);
    alloc_kernel<<<80, 256, 0, stream>>>();
    scatter_kernel<<<(E + 255) / 256, 256, 0, stream>>>(edge_dst, edge_type);
    msg_kernel<<<E / 32, 256, 0, stream>>>(h, edge_norm, edge_src, edge_type);
    node_kernel<<<N / 8, 128, 0, stream>>>(h, node_norm, h_bias, loop_weight,
                                           time_embed, time_idx, out);
}